// Round 1
// baseline (835.253 us; speedup 1.0000x reference)
//
#include <hip/hip_runtime.h>

// Problem constants (from reference): B=2048, K=1024, D=64, C=32
#define BQ 2048
#define KK 1024
#define DD 64
#define CC 32

__global__ __launch_bounds__(256) void nw_attn_kernel(
    const float* __restrict__ x,
    const float* __restrict__ keys,
    const float* __restrict__ values,
    const float* __restrict__ gamma,
    float* __restrict__ out)
{
    const int b    = blockIdx.x;
    const int t    = threadIdx.x;
    const int lane = t & 63;
    const int wave = t >> 6;

    __shared__ float s_w[KK];        // metric -> softmax weights
    __shared__ float s_red[8];       // cross-wave max / sum
    __shared__ float s_part[4][CC];  // per-wave partial output

    const float g = gamma[0];

    const float4* x4 = (const float4*)x;
    const float4* k4 = (const float4*)keys;
    const float4* v4 = (const float4*)values;

    // ---------------- Phase 1: metric[k] = ||x - key_k||^2 ----------------
    // 16 lanes per key (float4 over D=64); each wave: 4 consecutive keys.
    const int sub = lane & 15;   // which float4 chunk of D
    const int kj  = lane >> 4;   // key sub-index within wave (0..3)
    const float4 xv = x4[b * (DD / 4) + sub];

    const size_t kbase = (size_t)b * (KK * DD / 4);
    for (int it = 0; it < KK / 16; ++it) {
        const int k = it * 16 + wave * 4 + kj;
        const float4 kv = k4[kbase + (size_t)k * (DD / 4) + sub];
        const float dx = xv.x - kv.x;
        const float dy = xv.y - kv.y;
        const float dz = xv.z - kv.z;
        const float dw = xv.w - kv.w;
        float m = dx * dx + dy * dy + dz * dz + dw * dw;
        // reduce across the 16 lanes of this key-group
        m += __shfl_xor(m, 1);
        m += __shfl_xor(m, 2);
        m += __shfl_xor(m, 4);
        m += __shfl_xor(m, 8);
        if (sub == 0) s_w[k] = -g * m;
    }
    __syncthreads();

    // ---------------- Phase 2: softmax over K in LDS ----------------
    const float v0 = s_w[t];
    const float v1 = s_w[t + 256];
    const float v2 = s_w[t + 512];
    const float v3 = s_w[t + 768];
    float lmax = fmaxf(fmaxf(v0, v1), fmaxf(v2, v3));
    #pragma unroll
    for (int off = 32; off >= 1; off >>= 1)
        lmax = fmaxf(lmax, __shfl_xor(lmax, off));
    if (lane == 0) s_red[wave] = lmax;
    __syncthreads();
    const float bmax = fmaxf(fmaxf(s_red[0], s_red[1]),
                             fmaxf(s_red[2], s_red[3]));

    const float e0 = __expf(v0 - bmax);
    const float e1 = __expf(v1 - bmax);
    const float e2 = __expf(v2 - bmax);
    const float e3 = __expf(v3 - bmax);
    s_w[t]       = e0;
    s_w[t + 256] = e1;
    s_w[t + 512] = e2;
    s_w[t + 768] = e3;
    float lsum = e0 + e1 + e2 + e3;
    #pragma unroll
    for (int off = 32; off >= 1; off >>= 1)
        lsum += __shfl_xor(lsum, off);
    if (lane == 0) s_red[4 + wave] = lsum;
    __syncthreads();
    const float inv_sum = 1.0f / (s_red[4] + s_red[5] + s_red[6] + s_red[7]);

    // ---------------- Phase 3: pred[c] = sum_k w[k] * values[k][c] ----------------
    // 8 lanes per key (float4 over C=32); each wave: 8 consecutive keys.
    const int ci  = lane & 7;    // c-group: covers c = 4*ci .. 4*ci+3
    const int kj3 = lane >> 3;   // key sub-index within wave (0..7)
    float4 acc = make_float4(0.f, 0.f, 0.f, 0.f);

    const size_t vbase = (size_t)b * (KK * CC / 4);
    for (int it = 0; it < KK / 32; ++it) {
        const int k = it * 32 + wave * 8 + kj3;
        const float4 vv = v4[vbase + (size_t)k * (CC / 4) + ci];
        const float p = s_w[k];
        acc.x += p * vv.x;
        acc.y += p * vv.y;
        acc.z += p * vv.z;
        acc.w += p * vv.w;
    }
    // reduce over key sub-groups within the wave (lanes differing in bits 3..5)
    #pragma unroll
    for (int off = 8; off <= 32; off <<= 1) {
        acc.x += __shfl_xor(acc.x, off);
        acc.y += __shfl_xor(acc.y, off);
        acc.z += __shfl_xor(acc.z, off);
        acc.w += __shfl_xor(acc.w, off);
    }
    if (kj3 == 0) {
        s_part[wave][ci * 4 + 0] = acc.x;
        s_part[wave][ci * 4 + 1] = acc.y;
        s_part[wave][ci * 4 + 2] = acc.z;
        s_part[wave][ci * 4 + 3] = acc.w;
    }
    __syncthreads();
    if (t < CC) {
        const float r = (s_part[0][t] + s_part[1][t] +
                         s_part[2][t] + s_part[3][t]) * inv_sum;
        out[b * CC + t] = r;
    }
}

extern "C" void kernel_launch(void* const* d_in, const int* in_sizes, int n_in,
                              void* d_out, int out_size, void* d_ws, size_t ws_size,
                              hipStream_t stream) {
    const float* x      = (const float*)d_in[0];
    const float* keys   = (const float*)d_in[1];
    const float* values = (const float*)d_in[2];
    const float* gamma  = (const float*)d_in[3];
    float* out = (float*)d_out;

    const int b = in_sizes[0] / DD;   // 2048
    nw_attn_kernel<<<dim3(b), dim3(256), 0, stream>>>(x, keys, values, gamma, out);
}